// Round 10
// baseline (1781.967 us; speedup 1.0000x reference)
//
#include <hip/hip_runtime.h>
#include <hip/hip_bf16.h>

// GINE 3-conv GNN. Dst-grouped slot layout (round-8 zero-global-atomic build,
// all-cached loads — NT-load experiment reverted). New: fused conv kernels.
//   nrec[n] = 64B interleaved {Pa|X} per 4-dim group -> ONE cache line per edge
//   serves both the edge-MLP's Pa[s] gather and the message's X[s] gather.
//   convF: 4 lanes/node walk the slot segment; edge MLP in-register via
//   4-lane shfl exchange; Pc[t]=Pc[n] loaded once per node; msg accumulated in
//   registers -> direct agg store (no atomics, no separate kagg kernels).
//   conv3's edge head split into khead (stream ebuf+srec -> out_e scatter).
// N=100000, E=3200000, H=16. fp32 in/out; edge_index int32 rows [src | dst].
//
// ws (137.6 MB):
//   ebuf [E][16] bf16 (102.4M); build scratch aliases inside (dead before conv1):
//       brec16 [E] uint4 (51.2M), hist [782][1024] int (3.2M), binsum, binbase
//   srec [E] u64 (25.6M) {src:17,dst:17,eid:22}
//   nrec [N][32] bf16 (6.4M), Pc [N][16] bf16 (3.2M)
// out_n region: start[N+1] (dead before node_last). out_e region: ea_s [E]8B +
//   agg [N][16] f32 (both dead before khead writes out_e).

#define NN 100000
#define NE 3200000
#define NBKT 782          // ceil(NN/128)
#define BSHIFT 7
#define LMASK 127
#define NBLK1 1024        // pass-1 blocks
#define EPB1 3125         // NE / NBLK1 (exact)

__device__ __forceinline__ float bf2f(unsigned int h) {
    unsigned int u = h << 16;
    float f; __builtin_memcpy(&f, &u, 4); return f;
}
__device__ __forceinline__ unsigned short f2bf(float f) {
    unsigned int u; __builtin_memcpy(&u, &f, 4);
    u += 0x7fffu + ((u >> 16) & 1u);          // RNE
    return (unsigned short)(u >> 16);
}
__device__ __forceinline__ void unpk4(uint2 w, float* r) {
    r[0] = bf2f(w.x & 0xffffu); r[1] = bf2f(w.x >> 16);
    r[2] = bf2f(w.y & 0xffffu); r[3] = bf2f(w.y >> 16);
}
__device__ __forceinline__ void ldbf16x16(const unsigned short* p, float* r) {
    const uint4* q = reinterpret_cast<const uint4*>(p);
    uint4 a = q[0], b = q[1];
    unsigned int w[8] = {a.x, a.y, a.z, a.w, b.x, b.y, b.z, b.w};
    #pragma unroll
    for (int k = 0; k < 8; ++k) {
        r[2*k]   = bf2f(w[k] & 0xffffu);
        r[2*k+1] = bf2f(w[k] >> 16);
    }
}
__device__ __forceinline__ void stbf16x16(unsigned short* p, const float* r) {
    unsigned int w[8];
    #pragma unroll
    for (int k = 0; k < 8; ++k)
        w[k] = (unsigned int)f2bf(r[2*k]) | ((unsigned int)f2bf(r[2*k+1]) << 16);
    uint4* q = reinterpret_cast<uint4*>(p);
    q[0] = make_uint4(w[0], w[1], w[2], w[3]);
    q[1] = make_uint4(w[4], w[5], w[6], w[7]);
}
// nrec row: group g (dims 4g..4g+3): [g*8 .. g*8+3]=Pa, [g*8+4 .. g*8+7]=X
__device__ __forceinline__ void st_nrec16(unsigned short* p, const float* pa, const float* xv) {
    #pragma unroll
    for (int g = 0; g < 4; ++g) {
        uint4 w;
        w.x = (unsigned)f2bf(pa[4*g])   | ((unsigned)f2bf(pa[4*g+1]) << 16);
        w.y = (unsigned)f2bf(pa[4*g+2]) | ((unsigned)f2bf(pa[4*g+3]) << 16);
        w.z = (unsigned)f2bf(xv[4*g])   | ((unsigned)f2bf(xv[4*g+1]) << 16);
        w.w = (unsigned)f2bf(xv[4*g+2]) | ((unsigned)f2bf(xv[4*g+3]) << 16);
        *reinterpret_cast<uint4*>(p + g*8) = w;
    }
}
__device__ __forceinline__ void ld_X16(const unsigned short* p, float* xv) {
    #pragma unroll
    for (int g = 0; g < 4; ++g) {
        uint2 w = *reinterpret_cast<const uint2*>(p + g*8 + 4);
        unpk4(w, xv + 4*g);
    }
}

// ---------------- build: two-level counting sort (round-8, cached) ----------------

__global__ void khist1(const int* __restrict__ ei, int* __restrict__ hist) {
    __shared__ int h[NBKT];
    int blk = blockIdx.x, tid = threadIdx.x;
    for (int b = tid; b < NBKT; b += 256) h[b] = 0;
    __syncthreads();
    int e0 = blk * EPB1;
    for (int e = e0 + tid; e < e0 + EPB1; e += 256)
        atomicAdd(&h[ei[NE + e] >> BSHIFT], 1);     // LDS atomic
    __syncthreads();
    for (int b = tid; b < NBKT; b += 256) hist[b * NBLK1 + blk] = h[b];
}

__global__ void kscan_a(int* __restrict__ hist, int* __restrict__ binsum) {
    __shared__ int s[NBLK1];
    int b = blockIdx.x, t = threadIdx.x;
    int v = hist[b * NBLK1 + t];
    s[t] = v; __syncthreads();
    for (int off = 1; off < NBLK1; off <<= 1) {
        int u = (t >= off) ? s[t - off] : 0;
        __syncthreads();
        s[t] += u;
        __syncthreads();
    }
    hist[b * NBLK1 + t] = s[t] - v;
    if (t == NBLK1 - 1) binsum[b] = s[t];
}

__global__ void kscan_b(const int* __restrict__ binsum, int* __restrict__ binbase,
                        int* __restrict__ start) {
    __shared__ int s[1024];
    int t = threadIdx.x;
    int v = (t < NBKT) ? binsum[t] : 0;
    s[t] = v; __syncthreads();
    for (int off = 1; off < 1024; off <<= 1) {
        int u = (t >= off) ? s[t - off] : 0;
        __syncthreads();
        s[t] += u;
        __syncthreads();
    }
    if (t < NBKT) binbase[t] = s[t] - v;
    if (t == NBKT - 1) binbase[NBKT] = s[t];        // == NE
    if (t == 0) start[NN] = NE;
}

__global__ void kscatter1(const int* __restrict__ ei, const float* __restrict__ ea,
                          const int* __restrict__ hist, const int* __restrict__ binbase,
                          uint4* __restrict__ brec16) {
    __shared__ int cur[NBKT];
    int blk = blockIdx.x, tid = threadIdx.x;
    for (int b = tid; b < NBKT; b += 256)
        cur[b] = binbase[b] + hist[b * NBLK1 + blk];
    __syncthreads();
    int e0 = blk * EPB1;
    for (int e = e0 + tid; e < e0 + EPB1; e += 256) {
        int s = ei[e], d = ei[NE + e];
        float f0 = ea[(size_t)3*e], f1 = ea[(size_t)3*e+1], f2 = ea[(size_t)3*e+2];
        int pos = atomicAdd(&cur[d >> BSHIFT], 1);  // LDS atomic
        unsigned long long u = (unsigned long long)(unsigned int)s
                             | ((unsigned long long)(unsigned int)d << 17)
                             | ((unsigned long long)(unsigned int)e << 34);
        uint4 r;
        r.x = (unsigned int)u;
        r.y = (unsigned int)(u >> 32);
        r.z = (unsigned int)f2bf(f0) | ((unsigned int)f2bf(f1) << 16);
        r.w = (unsigned int)f2bf(f2);
        brec16[pos] = r;
    }
}

__global__ void kbucket(const uint4* __restrict__ brec16, const int* __restrict__ binbase,
                        unsigned long long* __restrict__ srec, unsigned int* __restrict__ ea_s,
                        int* __restrict__ start) {
    __shared__ int cnt[128];
    __shared__ int off[128];
    __shared__ int cur[128];
    int bkt = blockIdx.x, t = threadIdx.x;
    int base = binbase[bkt], end = binbase[bkt + 1];
    if (t < 128) cnt[t] = 0;
    __syncthreads();
    for (int j = base + t; j < end; j += 256) {
        uint4 r = brec16[j];
        int dl = (int)(((r.x >> 17) | (r.y << 15)) & 0x1FFFFu) & LMASK;
        atomicAdd(&cnt[dl], 1);
    }
    __syncthreads();
    if (t < 128) { off[t] = cnt[t]; }
    __syncthreads();
    for (int o = 1; o < 128; o <<= 1) {
        int u = (t < 128 && t >= o) ? off[t - o] : 0;
        __syncthreads();
        if (t < 128) off[t] += u;
        __syncthreads();
    }
    if (t < 128) {
        int excl = off[t] - cnt[t];
        int node = bkt * 128 + t;
        if (node < NN) start[node] = base + excl;
        cur[t] = base + excl;
    }
    __syncthreads();
    for (int j = base + t; j < end; j += 256) {
        uint4 r = brec16[j];
        int dl = (int)(((r.x >> 17) | (r.y << 15)) & 0x1FFFFu) & LMASK;
        int p = atomicAdd(&cur[dl], 1);
        srec[p] = (unsigned long long)r.x | ((unsigned long long)r.y << 32);
        *reinterpret_cast<uint2*>(&ea_s[(size_t)2*p]) = make_uint2(r.z, r.w);
    }
}

// ---------------- node-side kernels ----------------

__global__ void prep1(const float* __restrict__ x, const float* __restrict__ ew1,
                      unsigned short* __restrict__ nrec, unsigned short* __restrict__ Pc) {
    int n = blockIdx.x * blockDim.x + threadIdx.x;
    if (n >= NN) return;
    float x0 = x[3*n], x1 = x[3*n+1], x2 = x[3*n+2];
    float pa[16], pc[16], xv[16];
    #pragma unroll
    for (int j = 0; j < 16; ++j) {
        pa[j] = x0*ew1[0*16+j] + x1*ew1[1*16+j] + x2*ew1[2*16+j];
        pc[j] = x0*ew1[6*16+j] + x1*ew1[7*16+j] + x2*ew1[8*16+j];
        xv[j] = 0.f;
    }
    xv[0] = x0; xv[1] = x1; xv[2] = x2;
    st_nrec16(nrec + (size_t)n*32, pa, xv);
    stbf16x16(Pc + (size_t)n*16, pc);
}

__global__ void conv1_node(const float* __restrict__ agg, const float* __restrict__ x,
                           const float* __restrict__ nw1, const float* __restrict__ nb1,
                           const float* __restrict__ nw2, const float* __restrict__ nb2,
                           const float* __restrict__ next_ew1,
                           unsigned short* __restrict__ nrec, unsigned short* __restrict__ Pc) {
    int n = blockIdx.x * blockDim.x + threadIdx.x;
    if (n >= NN) return;
    float o0 = agg[(size_t)n*16+0] + x[3*n];
    float o1 = agg[(size_t)n*16+1] + x[3*n+1];
    float o2 = agg[(size_t)n*16+2] + x[3*n+2];
    float h[16];
    #pragma unroll
    for (int j = 0; j < 16; ++j)
        h[j] = fmaxf(nb1[j] + o0*nw1[0*16+j] + o1*nw1[1*16+j] + o2*nw1[2*16+j], 0.f);
    float xn[16];
    #pragma unroll
    for (int j = 0; j < 16; ++j) {
        float a = nb2[j];
        #pragma unroll
        for (int i = 0; i < 16; ++i) a = fmaf(h[i], nw2[i*16+j], a);
        xn[j] = fmaxf(a, 0.f);
    }
    float pa[16], pc[16];
    #pragma unroll
    for (int j = 0; j < 16; ++j) {
        float sa = 0.f, sc = 0.f;
        #pragma unroll
        for (int i = 0; i < 16; ++i) {
            sa = fmaf(xn[i], next_ew1[i*16+j], sa);
            sc = fmaf(xn[i], next_ew1[(32+i)*16+j], sc);
        }
        pa[j] = sa; pc[j] = sc;
    }
    st_nrec16(nrec + (size_t)n*32, pa, xn);
    stbf16x16(Pc + (size_t)n*16, pc);
}

__global__ void node_mid(const float* __restrict__ agg,
                         const float* __restrict__ nw1, const float* __restrict__ nb1,
                         const float* __restrict__ nw2, const float* __restrict__ nb2,
                         const float* __restrict__ next_ew1,
                         unsigned short* nrec, unsigned short* __restrict__ Pc) {
    int n = blockIdx.x * blockDim.x + threadIdx.x;
    if (n >= NN) return;
    float o[16];
    ld_X16(nrec + (size_t)n*32, o);
    #pragma unroll
    for (int j = 0; j < 16; ++j) o[j] += agg[(size_t)n*16 + j];
    float h[16];
    #pragma unroll
    for (int j = 0; j < 16; ++j) {
        float a = nb1[j];
        #pragma unroll
        for (int i = 0; i < 16; ++i) a = fmaf(o[i], nw1[i*16+j], a);
        h[j] = fmaxf(a, 0.f);
    }
    float xn[16];
    #pragma unroll
    for (int j = 0; j < 16; ++j) {
        float a = nb2[j];
        #pragma unroll
        for (int i = 0; i < 16; ++i) a = fmaf(h[i], nw2[i*16+j], a);
        xn[j] = fmaxf(a, 0.f);
    }
    float pa[16], pc[16];
    #pragma unroll
    for (int j = 0; j < 16; ++j) {
        float sa = 0.f, sc = 0.f;
        #pragma unroll
        for (int i = 0; i < 16; ++i) {
            sa = fmaf(xn[i], next_ew1[i*16+j], sa);
            sc = fmaf(xn[i], next_ew1[(32+i)*16+j], sc);
        }
        pa[j] = sa; pc[j] = sc;
    }
    st_nrec16(nrec + (size_t)n*32, pa, xn);
    stbf16x16(Pc + (size_t)n*16, pc);
}

__global__ void node_last(const float* __restrict__ agg, const unsigned short* __restrict__ nrec,
                          const float* __restrict__ nw1, const float* __restrict__ nb1,
                          const float* __restrict__ nw2, const float* __restrict__ nb2,
                          const float* __restrict__ hw1, const float* __restrict__ hb1,
                          const float* __restrict__ hw2, const float* __restrict__ hb2,
                          float* __restrict__ out_n) {
    int n = blockIdx.x * blockDim.x + threadIdx.x;
    if (n >= NN) return;
    float o[16];
    ld_X16(nrec + (size_t)n*32, o);
    #pragma unroll
    for (int j = 0; j < 16; ++j) o[j] += agg[(size_t)n*16 + j];
    float h[16];
    #pragma unroll
    for (int j = 0; j < 16; ++j) {
        float a = nb1[j];
        #pragma unroll
        for (int i = 0; i < 16; ++i) a = fmaf(o[i], nw1[i*16+j], a);
        h[j] = fmaxf(a, 0.f);
    }
    float xn[16];
    #pragma unroll
    for (int j = 0; j < 16; ++j) {
        float a = nb2[j];
        #pragma unroll
        for (int i = 0; i < 16; ++i) a = fmaf(h[i], nw2[i*16+j], a);
        xn[j] = fmaxf(a, 0.f);
    }
    float g[16];
    #pragma unroll
    for (int j = 0; j < 16; ++j) {
        float a = hb1[j];
        #pragma unroll
        for (int i = 0; i < 16; ++i) a = fmaf(xn[i], hw1[i*16+j], a);
        g[j] = fmaxf(a, 0.f);
    }
    #pragma unroll
    for (int k = 0; k < 3; ++k) {
        float a = hb2[k];
        #pragma unroll
        for (int i = 0; i < 16; ++i) a = fmaf(g[i], hw2[i*3+k], a);
        out_n[(size_t)n*3 + k] = a;
    }
}

// ---------------- fused conv kernels: 4 lanes/node walk the slot segment ----------------

// conv1: edge MLP (ea input) + msg3 aggregation. ebuf written; agg3 written.
__global__ void conv1F(const int* __restrict__ start, const unsigned long long* __restrict__ srec,
                       const unsigned int* __restrict__ ea_s,
                       const unsigned short* __restrict__ nrec, const unsigned short* __restrict__ Pc,
                       const float* __restrict__ ew1, const float* __restrict__ eb1,
                       const float* __restrict__ ew2, const float* __restrict__ eb2,
                       unsigned short* __restrict__ ebuf, float* __restrict__ agg) {
    int tg = blockIdx.x * blockDim.x + threadIdx.x;
    int n = tg >> 2, q = tg & 3;
    if (n >= NN) return;
    int lane = threadIdx.x & 63;
    int base = lane & ~3;
    int j0 = start[n], j1 = start[n + 1];
    float pcq[4], b1q[4], b2q[4];
    unpk4(*reinterpret_cast<const uint2*>(Pc + (size_t)n*16 + q*4), pcq);
    #pragma unroll
    for (int d = 0; d < 4; ++d) { b1q[d] = eb1[q*4+d]; b2q[d] = eb2[q*4+d]; }
    float a0 = 0.f, a1 = 0.f, a2 = 0.f;
    for (int j = j0; j < j1; ++j) {
        unsigned long long sr = srec[j];
        int s = (int)(sr & 0x1FFFFu);
        uint2 eaw = *reinterpret_cast<const uint2*>(&ea_s[(size_t)2*j]);
        float e0 = bf2f(eaw.x & 0xffffu), e1 = bf2f(eaw.x >> 16), e2 = bf2f(eaw.y & 0xffffu);
        uint4 nx = *reinterpret_cast<const uint4*>(nrec + (size_t)s*32 + q*8);
        float paq[4]; unpk4(make_uint2(nx.x, nx.y), paq);
        float xq[4];  unpk4(make_uint2(nx.z, nx.w), xq);
        float h[4];
        #pragma unroll
        for (int d = 0; d < 4; ++d) {
            float a = paq[d] + pcq[d] + b1q[d]
                    + e0*ew1[3*16 + q*4 + d] + e1*ew1[4*16 + q*4 + d] + e2*ew1[5*16 + q*4 + d];
            h[d] = fmaxf(a, 0.f);
        }
        float hall[16];
        #pragma unroll
        for (int sq = 0; sq < 4; ++sq) {
            #pragma unroll
            for (int d = 0; d < 4; ++d) hall[4*sq + d] = __shfl(h[d], base + sq, 64);
        }
        float h2[4];
        #pragma unroll
        for (int d = 0; d < 4; ++d) {
            float a = b2q[d];
            #pragma unroll
            for (int i = 0; i < 16; ++i) a = fmaf(hall[i], ew2[i*16 + q*4 + d], a);
            h2[d] = fmaxf(a, 0.f);
        }
        unsigned int o0w = (unsigned)f2bf(h2[0]) | ((unsigned)f2bf(h2[1]) << 16);
        unsigned int o1w = (unsigned)f2bf(h2[2]) | ((unsigned)f2bf(h2[3]) << 16);
        *reinterpret_cast<uint2*>(ebuf + (size_t)j*16 + q*4) = make_uint2(o0w, o1w);
        if (q == 0) {
            a0 += fmaxf(xq[0] + e0, 0.f);
            a1 += fmaxf(xq[1] + e1, 0.f);
            a2 += fmaxf(xq[2] + e2, 0.f);
        }
    }
    if (q == 0) {
        float* p = agg + (size_t)n*16;
        p[0] = a0; p[1] = a1; p[2] = a2;
    }
}

// conv2/3: edge MLP (ebuf in-place) + msg16 aggregation (direct agg store).
__global__ void convF(const int* __restrict__ start, const unsigned long long* __restrict__ srec,
                      unsigned short* ebuf,
                      const unsigned short* __restrict__ nrec, const unsigned short* __restrict__ Pc,
                      const float* __restrict__ ew1, const float* __restrict__ eb1,
                      const float* __restrict__ ew2, const float* __restrict__ eb2,
                      float* __restrict__ agg) {
    int tg = blockIdx.x * blockDim.x + threadIdx.x;
    int n = tg >> 2, q = tg & 3;
    if (n >= NN) return;
    int lane = threadIdx.x & 63;
    int base = lane & ~3;
    int j0 = start[n], j1 = start[n + 1];
    float pcq[4], b1q[4], b2q[4];
    unpk4(*reinterpret_cast<const uint2*>(Pc + (size_t)n*16 + q*4), pcq);
    #pragma unroll
    for (int d = 0; d < 4; ++d) { b1q[d] = eb1[q*4+d]; b2q[d] = eb2[q*4+d]; }
    float acc[4] = {0.f, 0.f, 0.f, 0.f};
    for (int j = j0; j < j1; ++j) {
        unsigned long long sr = srec[j];
        int s = (int)(sr & 0x1FFFFu);
        uint2 eb = *reinterpret_cast<const uint2*>(ebuf + (size_t)j*16 + q*4);
        uint4 nx = *reinterpret_cast<const uint4*>(nrec + (size_t)s*32 + q*8);
        float paq[4]; unpk4(make_uint2(nx.x, nx.y), paq);
        float xq[4];  unpk4(make_uint2(nx.z, nx.w), xq);
        float einq[4]; unpk4(eb, einq);
        // share ein across the 4-lane group
        float ein[16];
        #pragma unroll
        for (int sq = 0; sq < 4; ++sq) {
            unsigned int ax = (unsigned int)__shfl((int)eb.x, base + sq, 64);
            unsigned int ay = (unsigned int)__shfl((int)eb.y, base + sq, 64);
            ein[4*sq+0] = bf2f(ax & 0xffffu); ein[4*sq+1] = bf2f(ax >> 16);
            ein[4*sq+2] = bf2f(ay & 0xffffu); ein[4*sq+3] = bf2f(ay >> 16);
        }
        float h[4];
        #pragma unroll
        for (int d = 0; d < 4; ++d) {
            float a = paq[d] + pcq[d] + b1q[d];
            #pragma unroll
            for (int i = 0; i < 16; ++i) a = fmaf(ein[i], ew1[(16+i)*16 + q*4 + d], a);
            h[d] = fmaxf(a, 0.f);
        }
        float hall[16];
        #pragma unroll
        for (int sq = 0; sq < 4; ++sq) {
            #pragma unroll
            for (int d = 0; d < 4; ++d) hall[4*sq + d] = __shfl(h[d], base + sq, 64);
        }
        float h2[4];
        #pragma unroll
        for (int d = 0; d < 4; ++d) {
            float a = b2q[d];
            #pragma unroll
            for (int i = 0; i < 16; ++i) a = fmaf(hall[i], ew2[i*16 + q*4 + d], a);
            h2[d] = fmaxf(a, 0.f);
        }
        unsigned int o0w = (unsigned)f2bf(h2[0]) | ((unsigned)f2bf(h2[1]) << 16);
        unsigned int o1w = (unsigned)f2bf(h2[2]) | ((unsigned)f2bf(h2[3]) << 16);
        *reinterpret_cast<uint2*>(ebuf + (size_t)j*16 + q*4) = make_uint2(o0w, o1w);
        #pragma unroll
        for (int d = 0; d < 4; ++d) acc[d] += fmaxf(xq[d] + einq[d], 0.f);
    }
    *reinterpret_cast<float4*>(agg + (size_t)n*16 + q*4) = make_float4(acc[0], acc[1], acc[2], acc[3]);
}

// conv3 edge head: stream ebuf3 + srec -> out_e scatter (runs after node_last).
__global__ void khead(const unsigned long long* __restrict__ srec,
                      const unsigned short* __restrict__ ebuf,
                      const float* __restrict__ hw1, const float* __restrict__ hb1,
                      const float* __restrict__ hw2, const float* __restrict__ hb2,
                      float* __restrict__ out_e) {
    int j = blockIdx.x * blockDim.x + threadIdx.x;
    if (j >= NE) return;
    unsigned long long sr = srec[j];
    int e = (int)(sr >> 34);
    float h2[16];
    ldbf16x16(ebuf + (size_t)j*16, h2);
    float g[16];
    #pragma unroll
    for (int jj = 0; jj < 16; ++jj) {
        float a = hb1[jj];
        #pragma unroll
        for (int i = 0; i < 16; ++i) a = fmaf(h2[i], hw1[i*16+jj], a);
        g[jj] = fmaxf(a, 0.f);
    }
    #pragma unroll
    for (int k = 0; k < 3; ++k) {
        float a = hb2[k];
        #pragma unroll
        for (int i = 0; i < 16; ++i) a = fmaf(g[i], hw2[i*3+k], a);
        out_e[(size_t)e*3 + k] = a;
    }
}

extern "C" void kernel_launch(void* const* d_in, const int* in_sizes, int n_in,
                              void* d_out, int out_size, void* d_ws, size_t ws_size,
                              hipStream_t stream) {
    const float* x  = (const float*)d_in[0];
    const float* ea = (const float*)d_in[1];
    const int*   ei = (const int*)d_in[2];
    const float *c1_ew1 = (const float*)d_in[3],  *c1_eb1 = (const float*)d_in[4];
    const float *c1_ew2 = (const float*)d_in[5],  *c1_eb2 = (const float*)d_in[6];
    const float *c1_nw1 = (const float*)d_in[7],  *c1_nb1 = (const float*)d_in[8];
    const float *c1_nw2 = (const float*)d_in[9],  *c1_nb2 = (const float*)d_in[10];
    const float *c2_ew1 = (const float*)d_in[11], *c2_eb1 = (const float*)d_in[12];
    const float *c2_ew2 = (const float*)d_in[13], *c2_eb2 = (const float*)d_in[14];
    const float *c2_nw1 = (const float*)d_in[15], *c2_nb1 = (const float*)d_in[16];
    const float *c2_nw2 = (const float*)d_in[17], *c2_nb2 = (const float*)d_in[18];
    const float *c3_ew1 = (const float*)d_in[19], *c3_eb1 = (const float*)d_in[20];
    const float *c3_ew2 = (const float*)d_in[21], *c3_eb2 = (const float*)d_in[22];
    const float *c3_nw1 = (const float*)d_in[23], *c3_nb1 = (const float*)d_in[24];
    const float *c3_nw2 = (const float*)d_in[25], *c3_nb2 = (const float*)d_in[26];
    const float *node_w1 = (const float*)d_in[27], *node_b1 = (const float*)d_in[28];
    const float *node_w2 = (const float*)d_in[29], *node_b2 = (const float*)d_in[30];
    const float *edge_w1 = (const float*)d_in[31], *edge_b1 = (const float*)d_in[32];
    const float *edge_w2 = (const float*)d_in[33], *edge_b2 = (const float*)d_in[34];

    // ---- ws carve-up (137.6 MB) ----
    char* w = (char*)d_ws;
    unsigned short* ebuf = (unsigned short*)w;               // NE*32; build scratch aliases inside:
    uint4* brec16 = (uint4*)w;                               //   NE*16 = 51.2 MB
    int* hist   = (int*)(w + (size_t)NE*16);                 //   NBKT*NBLK1*4 = 3.2 MB
    int* binsum = hist + NBKT * NBLK1;
    int* binbase = binsum + NBKT;
    w += (size_t)NE * 32;
    unsigned long long* srec = (unsigned long long*)w;  w += (size_t)NE * 8;   // 25.6 MB
    unsigned short* nrec = (unsigned short*)w;          w += (size_t)NN * 64;  // 6.4 MB
    unsigned short* Pc   = (unsigned short*)w;          w += (size_t)NN * 32;  // 3.2 MB

    // ---- d_out overlays ----
    float* out_n = (float*)d_out;                      // N*3 floats
    float* out_e = out_n + (size_t)NN * 3;             // E*3 floats
    int* start = (int*)out_n;                          // (NN+1)*4, dead before node_last
    unsigned int* ea_s = (unsigned int*)out_e;                 // NE*8 = 25.6 MB
    float* agg = (float*)((char*)out_e + (size_t)NE * 8);      // N*16 f32 = 6.4 MB

    const int B = 256;
    const int gn = (NN + B - 1) / B;                 // 391
    const int ge = (NE + B - 1) / B;                 // 12500
    const int gq = (NN * 4 + B - 1) / B;             // 1563

    // ---- build (no global atomics) ----
    khist1<<<NBLK1, B, 0, stream>>>(ei, hist);
    kscan_a<<<NBKT, NBLK1, 0, stream>>>(hist, binsum);
    kscan_b<<<1, 1024, 0, stream>>>(binsum, binbase, start);
    kscatter1<<<NBLK1, B, 0, stream>>>(ei, ea, hist, binbase, brec16);
    kbucket<<<NBKT, B, 0, stream>>>(brec16, binbase, srec, ea_s, start);

    // ---- conv1 ----
    prep1<<<gn, B, 0, stream>>>(x, c1_ew1, nrec, Pc);
    conv1F<<<gq, B, 0, stream>>>(start, srec, ea_s, nrec, Pc,
                                 c1_ew1, c1_eb1, c1_ew2, c1_eb2, ebuf, agg);
    conv1_node<<<gn, B, 0, stream>>>(agg, x, c1_nw1, c1_nb1, c1_nw2, c1_nb2,
                                     c2_ew1, nrec, Pc);
    // ---- conv2 ----
    convF<<<gq, B, 0, stream>>>(start, srec, ebuf, nrec, Pc,
                                c2_ew1, c2_eb1, c2_ew2, c2_eb2, agg);
    node_mid<<<gn, B, 0, stream>>>(agg, c2_nw1, c2_nb1, c2_nw2, c2_nb2,
                                   c3_ew1, nrec, Pc);
    // ---- conv3 (agg consumed by node_last; khead then overwrites out_e) ----
    convF<<<gq, B, 0, stream>>>(start, srec, ebuf, nrec, Pc,
                                c3_ew1, c3_eb1, c3_ew2, c3_eb2, agg);
    node_last<<<gn, B, 0, stream>>>(agg, nrec, c3_nw1, c3_nb1, c3_nw2, c3_nb2,
                                    node_w1, node_b1, node_w2, node_b2, out_n);
    khead<<<ge, B, 0, stream>>>(srec, ebuf, edge_w1, edge_b1, edge_w2, edge_b2, out_e);
}

// Round 11
// 1451.408 us; speedup vs baseline: 1.2278x; 1.2278x over previous
//
#include <hip/hip_runtime.h>
#include <hip/hip_bf16.h>

// GINE 3-conv GNN. Round-8 zero-global-atomic counting-sort build (verbatim) +
// slot-parallel FUSED conv kernels: one block per 128-node bucket, one thread
// per slot does the full edge MLP in registers (round-8 conv_edge2 pattern),
// gathers Pa|X from one 64B nrec line, and accumulates the message into an LDS
// agg tile (ds_add_f32; dst-sorted => all segments bucket-interior => no
// global atomics). Replaces kagg16_s x2 / kagg3_s entirely.
// N=100000, E=3200000, H=16. fp32 in/out; edge_index int32 rows [src | dst].
//
// ws (137.6 MB):
//   ebuf [E][16] bf16 (102.4M); build scratch aliases inside (dead before conv1):
//       brec16 [E] uint4 (51.2M), hist [782][1024] int (3.2M), binsum, binbase
//   srec [E] u64 (25.6M) {src:17,dst:17,eid:22}
//   nrec [N][32] bf16 (6.4M) {Pa|X interleaved per 4-dim group}, Pc [N][16] bf16
// out_n region: start[N+1] (dead before node_last writes out_n)
// out_e region: ea_s [E] 8B (25.6M) + agg [N][16] f32 (6.4M)
//   (both dead before khead writes out_e)

#define NN 100000
#define NE 3200000
#define NBKT 782          // ceil(NN/128)
#define BSHIFT 7
#define LMASK 127
#define NBLK1 1024        // pass-1 blocks
#define EPB1 3125         // NE / NBLK1 (exact)

__device__ __forceinline__ float bf2f(unsigned int h) {
    unsigned int u = h << 16;
    float f; __builtin_memcpy(&f, &u, 4); return f;
}
__device__ __forceinline__ unsigned short f2bf(float f) {
    unsigned int u; __builtin_memcpy(&u, &f, 4);
    u += 0x7fffu + ((u >> 16) & 1u);          // RNE
    return (unsigned short)(u >> 16);
}
__device__ __forceinline__ void unpk4(uint2 w, float* r) {
    r[0] = bf2f(w.x & 0xffffu); r[1] = bf2f(w.x >> 16);
    r[2] = bf2f(w.y & 0xffffu); r[3] = bf2f(w.y >> 16);
}
__device__ __forceinline__ void ldbf16x16(const unsigned short* p, float* r) {
    const uint4* q = reinterpret_cast<const uint4*>(p);
    uint4 a = q[0], b = q[1];
    unsigned int w[8] = {a.x, a.y, a.z, a.w, b.x, b.y, b.z, b.w};
    #pragma unroll
    for (int k = 0; k < 8; ++k) {
        r[2*k]   = bf2f(w[k] & 0xffffu);
        r[2*k+1] = bf2f(w[k] >> 16);
    }
}
__device__ __forceinline__ void stbf16x16(unsigned short* p, const float* r) {
    unsigned int w[8];
    #pragma unroll
    for (int k = 0; k < 8; ++k)
        w[k] = (unsigned int)f2bf(r[2*k]) | ((unsigned int)f2bf(r[2*k+1]) << 16);
    uint4* q = reinterpret_cast<uint4*>(p);
    q[0] = make_uint4(w[0], w[1], w[2], w[3]);
    q[1] = make_uint4(w[4], w[5], w[6], w[7]);
}
// nrec row: group g (dims 4g..4g+3): [g*8 .. g*8+3]=Pa, [g*8+4 .. g*8+7]=X
__device__ __forceinline__ void st_nrec16(unsigned short* p, const float* pa, const float* xv) {
    #pragma unroll
    for (int g = 0; g < 4; ++g) {
        uint4 w;
        w.x = (unsigned)f2bf(pa[4*g])   | ((unsigned)f2bf(pa[4*g+1]) << 16);
        w.y = (unsigned)f2bf(pa[4*g+2]) | ((unsigned)f2bf(pa[4*g+3]) << 16);
        w.z = (unsigned)f2bf(xv[4*g])   | ((unsigned)f2bf(xv[4*g+1]) << 16);
        w.w = (unsigned)f2bf(xv[4*g+2]) | ((unsigned)f2bf(xv[4*g+3]) << 16);
        *reinterpret_cast<uint4*>(p + g*8) = w;
    }
}
__device__ __forceinline__ void ld_nrec16(const unsigned short* p, float* pa, float* xv) {
    #pragma unroll
    for (int g = 0; g < 4; ++g) {
        uint4 w = *reinterpret_cast<const uint4*>(p + g*8);
        unpk4(make_uint2(w.x, w.y), pa + 4*g);
        unpk4(make_uint2(w.z, w.w), xv + 4*g);
    }
}
__device__ __forceinline__ void ld_X16(const unsigned short* p, float* xv) {
    #pragma unroll
    for (int g = 0; g < 4; ++g) {
        uint2 w = *reinterpret_cast<const uint2*>(p + g*8 + 4);
        unpk4(w, xv + 4*g);
    }
}

// ---------------- build: two-level counting sort (round-8 verbatim) ----------------

__global__ void khist1(const int* __restrict__ ei, int* __restrict__ hist) {
    __shared__ int h[NBKT];
    int blk = blockIdx.x, tid = threadIdx.x;
    for (int b = tid; b < NBKT; b += 256) h[b] = 0;
    __syncthreads();
    int e0 = blk * EPB1;
    for (int e = e0 + tid; e < e0 + EPB1; e += 256)
        atomicAdd(&h[ei[NE + e] >> BSHIFT], 1);     // LDS atomic
    __syncthreads();
    for (int b = tid; b < NBKT; b += 256) hist[b * NBLK1 + blk] = h[b];
}

__global__ void kscan_a(int* __restrict__ hist, int* __restrict__ binsum) {
    __shared__ int s[NBLK1];
    int b = blockIdx.x, t = threadIdx.x;
    int v = hist[b * NBLK1 + t];
    s[t] = v; __syncthreads();
    for (int off = 1; off < NBLK1; off <<= 1) {
        int u = (t >= off) ? s[t - off] : 0;
        __syncthreads();
        s[t] += u;
        __syncthreads();
    }
    hist[b * NBLK1 + t] = s[t] - v;
    if (t == NBLK1 - 1) binsum[b] = s[t];
}

__global__ void kscan_b(const int* __restrict__ binsum, int* __restrict__ binbase,
                        int* __restrict__ start) {
    __shared__ int s[1024];
    int t = threadIdx.x;
    int v = (t < NBKT) ? binsum[t] : 0;
    s[t] = v; __syncthreads();
    for (int off = 1; off < 1024; off <<= 1) {
        int u = (t >= off) ? s[t - off] : 0;
        __syncthreads();
        s[t] += u;
        __syncthreads();
    }
    if (t < NBKT) binbase[t] = s[t] - v;
    if (t == NBKT - 1) binbase[NBKT] = s[t];        // == NE
    if (t == 0) start[NN] = NE;
}

__global__ void kscatter1(const int* __restrict__ ei, const float* __restrict__ ea,
                          const int* __restrict__ hist, const int* __restrict__ binbase,
                          uint4* __restrict__ brec16) {
    __shared__ int cur[NBKT];
    int blk = blockIdx.x, tid = threadIdx.x;
    for (int b = tid; b < NBKT; b += 256)
        cur[b] = binbase[b] + hist[b * NBLK1 + blk];
    __syncthreads();
    int e0 = blk * EPB1;
    for (int e = e0 + tid; e < e0 + EPB1; e += 256) {
        int s = ei[e], d = ei[NE + e];
        float f0 = ea[(size_t)3*e], f1 = ea[(size_t)3*e+1], f2 = ea[(size_t)3*e+2];
        int pos = atomicAdd(&cur[d >> BSHIFT], 1);  // LDS atomic
        unsigned long long u = (unsigned long long)(unsigned int)s
                             | ((unsigned long long)(unsigned int)d << 17)
                             | ((unsigned long long)(unsigned int)e << 34);
        uint4 r;
        r.x = (unsigned int)u;
        r.y = (unsigned int)(u >> 32);
        r.z = (unsigned int)f2bf(f0) | ((unsigned int)f2bf(f1) << 16);
        r.w = (unsigned int)f2bf(f2);
        brec16[pos] = r;
    }
}

__global__ void kbucket(const uint4* __restrict__ brec16, const int* __restrict__ binbase,
                        unsigned long long* __restrict__ srec, unsigned int* __restrict__ ea_s,
                        int* __restrict__ start) {
    __shared__ int cnt[128];
    __shared__ int off[128];
    __shared__ int cur[128];
    int bkt = blockIdx.x, t = threadIdx.x;
    int base = binbase[bkt], end = binbase[bkt + 1];
    if (t < 128) cnt[t] = 0;
    __syncthreads();
    for (int j = base + t; j < end; j += 256) {
        uint4 r = brec16[j];
        int dl = (int)(((r.x >> 17) | (r.y << 15)) & 0x1FFFFu) & LMASK;
        atomicAdd(&cnt[dl], 1);
    }
    __syncthreads();
    if (t < 128) { off[t] = cnt[t]; }
    __syncthreads();
    for (int o = 1; o < 128; o <<= 1) {
        int u = (t < 128 && t >= o) ? off[t - o] : 0;
        __syncthreads();
        if (t < 128) off[t] += u;
        __syncthreads();
    }
    if (t < 128) {
        int excl = off[t] - cnt[t];
        int node = bkt * 128 + t;
        if (node < NN) start[node] = base + excl;
        cur[t] = base + excl;
    }
    __syncthreads();
    for (int j = base + t; j < end; j += 256) {
        uint4 r = brec16[j];
        int dl = (int)(((r.x >> 17) | (r.y << 15)) & 0x1FFFFu) & LMASK;
        int p = atomicAdd(&cur[dl], 1);
        srec[p] = (unsigned long long)r.x | ((unsigned long long)r.y << 32);
        *reinterpret_cast<uint2*>(&ea_s[(size_t)2*p]) = make_uint2(r.z, r.w);
    }
}

// ---------------- node-side kernels (round-10 verbatim, verified) ----------------

__global__ void prep1(const float* __restrict__ x, const float* __restrict__ ew1,
                      unsigned short* __restrict__ nrec, unsigned short* __restrict__ Pc) {
    int n = blockIdx.x * blockDim.x + threadIdx.x;
    if (n >= NN) return;
    float x0 = x[3*n], x1 = x[3*n+1], x2 = x[3*n+2];
    float pa[16], pc[16], xv[16];
    #pragma unroll
    for (int j = 0; j < 16; ++j) {
        pa[j] = x0*ew1[0*16+j] + x1*ew1[1*16+j] + x2*ew1[2*16+j];
        pc[j] = x0*ew1[6*16+j] + x1*ew1[7*16+j] + x2*ew1[8*16+j];
        xv[j] = 0.f;
    }
    xv[0] = x0; xv[1] = x1; xv[2] = x2;
    st_nrec16(nrec + (size_t)n*32, pa, xv);
    stbf16x16(Pc + (size_t)n*16, pc);
}

__global__ void conv1_node(const float* __restrict__ agg, const float* __restrict__ x,
                           const float* __restrict__ nw1, const float* __restrict__ nb1,
                           const float* __restrict__ nw2, const float* __restrict__ nb2,
                           const float* __restrict__ next_ew1,
                           unsigned short* __restrict__ nrec, unsigned short* __restrict__ Pc) {
    int n = blockIdx.x * blockDim.x + threadIdx.x;
    if (n >= NN) return;
    float o0 = agg[(size_t)n*16+0] + x[3*n];
    float o1 = agg[(size_t)n*16+1] + x[3*n+1];
    float o2 = agg[(size_t)n*16+2] + x[3*n+2];
    float h[16];
    #pragma unroll
    for (int j = 0; j < 16; ++j)
        h[j] = fmaxf(nb1[j] + o0*nw1[0*16+j] + o1*nw1[1*16+j] + o2*nw1[2*16+j], 0.f);
    float xn[16];
    #pragma unroll
    for (int j = 0; j < 16; ++j) {
        float a = nb2[j];
        #pragma unroll
        for (int i = 0; i < 16; ++i) a = fmaf(h[i], nw2[i*16+j], a);
        xn[j] = fmaxf(a, 0.f);
    }
    float pa[16], pc[16];
    #pragma unroll
    for (int j = 0; j < 16; ++j) {
        float sa = 0.f, sc = 0.f;
        #pragma unroll
        for (int i = 0; i < 16; ++i) {
            sa = fmaf(xn[i], next_ew1[i*16+j], sa);
            sc = fmaf(xn[i], next_ew1[(32+i)*16+j], sc);
        }
        pa[j] = sa; pc[j] = sc;
    }
    st_nrec16(nrec + (size_t)n*32, pa, xn);
    stbf16x16(Pc + (size_t)n*16, pc);
}

__global__ void node_mid(const float* __restrict__ agg,
                         const float* __restrict__ nw1, const float* __restrict__ nb1,
                         const float* __restrict__ nw2, const float* __restrict__ nb2,
                         const float* __restrict__ next_ew1,
                         unsigned short* nrec, unsigned short* __restrict__ Pc) {
    int n = blockIdx.x * blockDim.x + threadIdx.x;
    if (n >= NN) return;
    float o[16];
    ld_X16(nrec + (size_t)n*32, o);
    #pragma unroll
    for (int j = 0; j < 16; ++j) o[j] += agg[(size_t)n*16 + j];
    float h[16];
    #pragma unroll
    for (int j = 0; j < 16; ++j) {
        float a = nb1[j];
        #pragma unroll
        for (int i = 0; i < 16; ++i) a = fmaf(o[i], nw1[i*16+j], a);
        h[j] = fmaxf(a, 0.f);
    }
    float xn[16];
    #pragma unroll
    for (int j = 0; j < 16; ++j) {
        float a = nb2[j];
        #pragma unroll
        for (int i = 0; i < 16; ++i) a = fmaf(h[i], nw2[i*16+j], a);
        xn[j] = fmaxf(a, 0.f);
    }
    float pa[16], pc[16];
    #pragma unroll
    for (int j = 0; j < 16; ++j) {
        float sa = 0.f, sc = 0.f;
        #pragma unroll
        for (int i = 0; i < 16; ++i) {
            sa = fmaf(xn[i], next_ew1[i*16+j], sa);
            sc = fmaf(xn[i], next_ew1[(32+i)*16+j], sc);
        }
        pa[j] = sa; pc[j] = sc;
    }
    st_nrec16(nrec + (size_t)n*32, pa, xn);
    stbf16x16(Pc + (size_t)n*16, pc);
}

__global__ void node_last(const float* __restrict__ agg, const unsigned short* __restrict__ nrec,
                          const float* __restrict__ nw1, const float* __restrict__ nb1,
                          const float* __restrict__ nw2, const float* __restrict__ nb2,
                          const float* __restrict__ hw1, const float* __restrict__ hb1,
                          const float* __restrict__ hw2, const float* __restrict__ hb2,
                          float* __restrict__ out_n) {
    int n = blockIdx.x * blockDim.x + threadIdx.x;
    if (n >= NN) return;
    float o[16];
    ld_X16(nrec + (size_t)n*32, o);
    #pragma unroll
    for (int j = 0; j < 16; ++j) o[j] += agg[(size_t)n*16 + j];
    float h[16];
    #pragma unroll
    for (int j = 0; j < 16; ++j) {
        float a = nb1[j];
        #pragma unroll
        for (int i = 0; i < 16; ++i) a = fmaf(o[i], nw1[i*16+j], a);
        h[j] = fmaxf(a, 0.f);
    }
    float xn[16];
    #pragma unroll
    for (int j = 0; j < 16; ++j) {
        float a = nb2[j];
        #pragma unroll
        for (int i = 0; i < 16; ++i) a = fmaf(h[i], nw2[i*16+j], a);
        xn[j] = fmaxf(a, 0.f);
    }
    float g[16];
    #pragma unroll
    for (int j = 0; j < 16; ++j) {
        float a = hb1[j];
        #pragma unroll
        for (int i = 0; i < 16; ++i) a = fmaf(xn[i], hw1[i*16+j], a);
        g[j] = fmaxf(a, 0.f);
    }
    #pragma unroll
    for (int k = 0; k < 3; ++k) {
        float a = hb2[k];
        #pragma unroll
        for (int i = 0; i < 16; ++i) a = fmaf(g[i], hw2[i*3+k], a);
        out_n[(size_t)n*3 + k] = a;
    }
}

// ------------- fused convs: slot-parallel, one block per bucket, LDS agg -------------

// conv1: one thread per slot; edge MLP (ea input) in registers; msg3 -> aggT LDS.
__global__ void conv1F(const int* __restrict__ start,
                       const unsigned long long* __restrict__ srec,
                       const unsigned int* __restrict__ ea_s,
                       const unsigned short* __restrict__ nrec, const unsigned short* __restrict__ Pcb,
                       const float* __restrict__ ew1, const float* __restrict__ eb1,
                       const float* __restrict__ ew2, const float* __restrict__ eb2,
                       unsigned short* __restrict__ ebuf, float* __restrict__ agg) {
    __shared__ float aggT[128 * 16];
    int bkt = blockIdx.x, tid = threadIdx.x;
    int n0 = bkt << BSHIFT;
    int n1 = min(n0 + 128, NN);
    int base = start[n0], end = start[n1];
    for (int i = tid; i < 128 * 16; i += 512) aggT[i] = 0.f;
    __syncthreads();
    for (int j = base + tid; j < end; j += 512) {
        unsigned long long sr = srec[j];
        int s = (int)(sr & 0x1FFFFu);
        int t = (int)((sr >> 17) & 0x1FFFFu);
        float pa[16], xv[16], pc[16];
        ld_nrec16(nrec + (size_t)s*32, pa, xv);      // one 64B line: Pa + X
        ldbf16x16(Pcb + (size_t)t*16, pc);           // dst-grouped, cached
        uint2 eaw = *reinterpret_cast<const uint2*>(&ea_s[(size_t)2*j]);
        float e0 = bf2f(eaw.x & 0xffffu), e1 = bf2f(eaw.x >> 16), e2 = bf2f(eaw.y & 0xffffu);
        float h[16];
        #pragma unroll
        for (int jj = 0; jj < 16; ++jj) {
            float a = pa[jj] + pc[jj] + eb1[jj]
                    + e0*ew1[3*16+jj] + e1*ew1[4*16+jj] + e2*ew1[5*16+jj];
            h[jj] = fmaxf(a, 0.f);
        }
        float h2[16];
        #pragma unroll
        for (int jj = 0; jj < 16; ++jj) {
            float a = eb2[jj];
            #pragma unroll
            for (int i = 0; i < 16; ++i) a = fmaf(h[i], ew2[i*16+jj], a);
            h2[jj] = fmaxf(a, 0.f);
        }
        stbf16x16(ebuf + (size_t)j*16, h2);
        int loc = (t & LMASK) * 16;
        atomicAdd(&aggT[loc + 0], fmaxf(xv[0] + e0, 0.f));
        atomicAdd(&aggT[loc + 1], fmaxf(xv[1] + e1, 0.f));
        atomicAdd(&aggT[loc + 2], fmaxf(xv[2] + e2, 0.f));
    }
    __syncthreads();
    for (int i = tid; i < 128 * 16; i += 512) {
        int node = n0 + (i >> 4);
        if (node < NN) agg[(size_t)node*16 + (i & 15)] = aggT[i];
    }
}

// conv2/3: one thread per slot; edge MLP (ebuf in-place) + msg16 -> aggT LDS.
__global__ void convF(const int* __restrict__ start,
                      const unsigned long long* __restrict__ srec,
                      unsigned short* ebuf,
                      const unsigned short* __restrict__ nrec, const unsigned short* __restrict__ Pcb,
                      const float* __restrict__ ew1, const float* __restrict__ eb1,
                      const float* __restrict__ ew2, const float* __restrict__ eb2,
                      float* __restrict__ agg) {
    __shared__ float aggT[128 * 16];
    int bkt = blockIdx.x, tid = threadIdx.x;
    int n0 = bkt << BSHIFT;
    int n1 = min(n0 + 128, NN);
    int base = start[n0], end = start[n1];
    for (int i = tid; i < 128 * 16; i += 512) aggT[i] = 0.f;
    __syncthreads();
    int rot = tid & 15;                              // stagger atomic dims
    for (int j = base + tid; j < end; j += 512) {
        unsigned long long sr = srec[j];
        int s = (int)(sr & 0x1FFFFu);
        int t = (int)((sr >> 17) & 0x1FFFFu);
        float pa[16], xv[16], pc[16], ein[16];
        ld_nrec16(nrec + (size_t)s*32, pa, xv);      // one 64B line: Pa + X
        ldbf16x16(Pcb + (size_t)t*16, pc);           // dst-grouped, cached
        ldbf16x16(ebuf + (size_t)j*16, ein);         // old edge feats (stream)
        float h[16];
        #pragma unroll
        for (int jj = 0; jj < 16; ++jj) h[jj] = pa[jj] + pc[jj] + eb1[jj];
        #pragma unroll
        for (int i = 0; i < 16; ++i) {
            #pragma unroll
            for (int jj = 0; jj < 16; ++jj) h[jj] = fmaf(ein[i], ew1[(16+i)*16+jj], h[jj]);
        }
        #pragma unroll
        for (int jj = 0; jj < 16; ++jj) h[jj] = fmaxf(h[jj], 0.f);
        float h2[16];
        #pragma unroll
        for (int jj = 0; jj < 16; ++jj) {
            float a = eb2[jj];
            #pragma unroll
            for (int i = 0; i < 16; ++i) a = fmaf(h[i], ew2[i*16+jj], a);
            h2[jj] = fmaxf(a, 0.f);
        }
        stbf16x16(ebuf + (size_t)j*16, h2);          // full 32B row, in place
        int loc = (t & LMASK) * 16;
        #pragma unroll
        for (int dd = 0; dd < 16; ++dd) {
            int d = (dd + rot) & 15;
            atomicAdd(&aggT[loc + d], fmaxf(xv[d] + ein[d], 0.f));
        }
    }
    __syncthreads();
    for (int i = tid; i < 128 * 16; i += 512) {
        int node = n0 + (i >> 4);
        if (node < NN) agg[(size_t)node*16 + (i & 15)] = aggT[i];
    }
}

// conv3 edge head: stream ebuf3 + srec -> out_e scatter (runs after node_last).
__global__ void khead(const unsigned long long* __restrict__ srec,
                      const unsigned short* __restrict__ ebuf,
                      const float* __restrict__ hw1, const float* __restrict__ hb1,
                      const float* __restrict__ hw2, const float* __restrict__ hb2,
                      float* __restrict__ out_e) {
    int j = blockIdx.x * blockDim.x + threadIdx.x;
    if (j >= NE) return;
    unsigned long long sr = srec[j];
    int e = (int)(sr >> 34);
    float h2[16];
    ldbf16x16(ebuf + (size_t)j*16, h2);
    float g[16];
    #pragma unroll
    for (int jj = 0; jj < 16; ++jj) {
        float a = hb1[jj];
        #pragma unroll
        for (int i = 0; i < 16; ++i) a = fmaf(h2[i], hw1[i*16+jj], a);
        g[jj] = fmaxf(a, 0.f);
    }
    #pragma unroll
    for (int k = 0; k < 3; ++k) {
        float a = hb2[k];
        #pragma unroll
        for (int i = 0; i < 16; ++i) a = fmaf(g[i], hw2[i*3+k], a);
        out_e[(size_t)e*3 + k] = a;
    }
}

extern "C" void kernel_launch(void* const* d_in, const int* in_sizes, int n_in,
                              void* d_out, int out_size, void* d_ws, size_t ws_size,
                              hipStream_t stream) {
    const float* x  = (const float*)d_in[0];
    const float* ea = (const float*)d_in[1];
    const int*   ei = (const int*)d_in[2];
    const float *c1_ew1 = (const float*)d_in[3],  *c1_eb1 = (const float*)d_in[4];
    const float *c1_ew2 = (const float*)d_in[5],  *c1_eb2 = (const float*)d_in[6];
    const float *c1_nw1 = (const float*)d_in[7],  *c1_nb1 = (const float*)d_in[8];
    const float *c1_nw2 = (const float*)d_in[9],  *c1_nb2 = (const float*)d_in[10];
    const float *c2_ew1 = (const float*)d_in[11], *c2_eb1 = (const float*)d_in[12];
    const float *c2_ew2 = (const float*)d_in[13], *c2_eb2 = (const float*)d_in[14];
    const float *c2_nw1 = (const float*)d_in[15], *c2_nb1 = (const float*)d_in[16];
    const float *c2_nw2 = (const float*)d_in[17], *c2_nb2 = (const float*)d_in[18];
    const float *c3_ew1 = (const float*)d_in[19], *c3_eb1 = (const float*)d_in[20];
    const float *c3_ew2 = (const float*)d_in[21], *c3_eb2 = (const float*)d_in[22];
    const float *c3_nw1 = (const float*)d_in[23], *c3_nb1 = (const float*)d_in[24];
    const float *c3_nw2 = (const float*)d_in[25], *c3_nb2 = (const float*)d_in[26];
    const float *node_w1 = (const float*)d_in[27], *node_b1 = (const float*)d_in[28];
    const float *node_w2 = (const float*)d_in[29], *node_b2 = (const float*)d_in[30];
    const float *edge_w1 = (const float*)d_in[31], *edge_b1 = (const float*)d_in[32];
    const float *edge_w2 = (const float*)d_in[33], *edge_b2 = (const float*)d_in[34];

    // ---- ws carve-up (137.6 MB) ----
    char* w = (char*)d_ws;
    unsigned short* ebuf = (unsigned short*)w;               // NE*32; build scratch aliases inside:
    uint4* brec16 = (uint4*)w;                               //   NE*16 = 51.2 MB
    int* hist   = (int*)(w + (size_t)NE*16);                 //   NBKT*NBLK1*4 = 3.2 MB
    int* binsum = hist + NBKT * NBLK1;
    int* binbase = binsum + NBKT;
    w += (size_t)NE * 32;
    unsigned long long* srec = (unsigned long long*)w;  w += (size_t)NE * 8;   // 25.6 MB
    unsigned short* nrec = (unsigned short*)w;          w += (size_t)NN * 64;  // 6.4 MB
    unsigned short* Pc   = (unsigned short*)w;          w += (size_t)NN * 32;  // 3.2 MB

    // ---- d_out overlays ----
    float* out_n = (float*)d_out;                      // N*3 floats
    float* out_e = out_n + (size_t)NN * 3;             // E*3 floats
    int* start = (int*)out_n;                          // (NN+1)*4, dead before node_last
    unsigned int* ea_s = (unsigned int*)out_e;                 // NE*8 = 25.6 MB
    float* agg = (float*)((char*)out_e + (size_t)NE * 8);      // N*16 f32 = 6.4 MB

    const int B = 256;
    const int gn = (NN + B - 1) / B;                 // 391
    const int ge = (NE + B - 1) / B;                 // 12500

    // ---- build (no global atomics; round-8 verbatim) ----
    khist1<<<NBLK1, B, 0, stream>>>(ei, hist);
    kscan_a<<<NBKT, NBLK1, 0, stream>>>(hist, binsum);
    kscan_b<<<1, 1024, 0, stream>>>(binsum, binbase, start);
    kscatter1<<<NBLK1, B, 0, stream>>>(ei, ea, hist, binbase, brec16);
    kbucket<<<NBKT, B, 0, stream>>>(brec16, binbase, srec, ea_s, start);

    // ---- conv1 (conv1F clobbers brec16/hist/binbase region via ebuf — all dead;
    //      bucket bounds derived from start[], not binbase) ----
    prep1<<<gn, B, 0, stream>>>(x, c1_ew1, nrec, Pc);
    conv1F<<<NBKT, 512, 0, stream>>>(start, srec, ea_s, nrec, Pc,
                                     c1_ew1, c1_eb1, c1_ew2, c1_eb2, ebuf, agg);
    conv1_node<<<gn, B, 0, stream>>>(agg, x, c1_nw1, c1_nb1, c1_nw2, c1_nb2,
                                     c2_ew1, nrec, Pc);
    // ---- conv2 ----
    convF<<<NBKT, 512, 0, stream>>>(start, srec, ebuf, nrec, Pc,
                                    c2_ew1, c2_eb1, c2_ew2, c2_eb2, agg);
    node_mid<<<gn, B, 0, stream>>>(agg, c2_nw1, c2_nb1, c2_nw2, c2_nb2,
                                   c3_ew1, nrec, Pc);
    // ---- conv3 (convF writes agg; node_last consumes agg then overwrites
    //      start region with out_n; khead finally overwrites ea_s/agg with out_e) ----
    convF<<<NBKT, 512, 0, stream>>>(start, srec, ebuf, nrec, Pc,
                                    c3_ew1, c3_eb1, c3_ew2, c3_eb2, agg);
    node_last<<<gn, B, 0, stream>>>(agg, nrec, c3_nw1, c3_nb1, c3_nw2, c3_nb2,
                                    node_w1, node_b1, node_w2, node_b2, out_n);
    khead<<<ge, B, 0, stream>>>(srec, ebuf, edge_w1, edge_b1, edge_w2, edge_b2, out_e);
}

// Round 12
// 511.146 us; speedup vs baseline: 3.4862x; 2.8395x over previous
//
#include <hip/hip_runtime.h>
#include <hip/hip_bf16.h>

// GINE 3-conv GNN. Round-8 zero-global-atomic counting-sort build (verbatim) +
// FUSED conv kernels with contention-free segmented reduction:
//   convE: 1 thread/slot (256/block, slot-major — proven round-8 access
//   pattern). Phase 1: full edge MLP in registers, nrec 64B line gives Pa+X in
//   one gather, msg=relu(X[s]+ein) -> padded LDS tile. Phase 2: segment heads
//   flagged by neighbor-t compare, Hillis-Steele enumerate, (seg,d) threads sum
//   segments; interior segs plain-store agg, boundary segs (<=2/block)
//   atomicAdd into pre-zeroed agg. No LDS atomics (round-11's serializer),
//   no separate kagg kernels (round-8's double line-tax).
// N=100000, E=3200000 (= 12500*256 exactly), H=16. fp32 in/out.
//
// ws (137.6 MB): ebuf[E][16]bf16 (build scratch brec16/hist/binsum/binbase
// aliased inside, dead before conv1); srec[E]u64; nrec[N][32]bf16 {Pa|X};
// Pc[N][16]bf16. out_n region: start[N+1] (unused after build; dead anyway).
// out_e region: ea_s[E]8B + agg[N][16]f32 (dead before khead writes out_e).

#define NN 100000
#define NE 3200000
#define NBKT 782          // ceil(NN/128)
#define BSHIFT 7
#define LMASK 127
#define NBLK1 1024        // pass-1 blocks
#define EPB1 3125         // NE / NBLK1 (exact)

__device__ __forceinline__ float bf2f(unsigned int h) {
    unsigned int u = h << 16;
    float f; __builtin_memcpy(&f, &u, 4); return f;
}
__device__ __forceinline__ unsigned short f2bf(float f) {
    unsigned int u; __builtin_memcpy(&u, &f, 4);
    u += 0x7fffu + ((u >> 16) & 1u);          // RNE
    return (unsigned short)(u >> 16);
}
__device__ __forceinline__ void unpk4(uint2 w, float* r) {
    r[0] = bf2f(w.x & 0xffffu); r[1] = bf2f(w.x >> 16);
    r[2] = bf2f(w.y & 0xffffu); r[3] = bf2f(w.y >> 16);
}
__device__ __forceinline__ void ldbf16x16(const unsigned short* p, float* r) {
    const uint4* q = reinterpret_cast<const uint4*>(p);
    uint4 a = q[0], b = q[1];
    unsigned int w[8] = {a.x, a.y, a.z, a.w, b.x, b.y, b.z, b.w};
    #pragma unroll
    for (int k = 0; k < 8; ++k) {
        r[2*k]   = bf2f(w[k] & 0xffffu);
        r[2*k+1] = bf2f(w[k] >> 16);
    }
}
__device__ __forceinline__ void stbf16x16(unsigned short* p, const float* r) {
    unsigned int w[8];
    #pragma unroll
    for (int k = 0; k < 8; ++k)
        w[k] = (unsigned int)f2bf(r[2*k]) | ((unsigned int)f2bf(r[2*k+1]) << 16);
    uint4* q = reinterpret_cast<uint4*>(p);
    q[0] = make_uint4(w[0], w[1], w[2], w[3]);
    q[1] = make_uint4(w[4], w[5], w[6], w[7]);
}
// nrec row: group g (dims 4g..4g+3): [g*8 .. g*8+3]=Pa, [g*8+4 .. g*8+7]=X
__device__ __forceinline__ void st_nrec16(unsigned short* p, const float* pa, const float* xv) {
    #pragma unroll
    for (int g = 0; g < 4; ++g) {
        uint4 w;
        w.x = (unsigned)f2bf(pa[4*g])   | ((unsigned)f2bf(pa[4*g+1]) << 16);
        w.y = (unsigned)f2bf(pa[4*g+2]) | ((unsigned)f2bf(pa[4*g+3]) << 16);
        w.z = (unsigned)f2bf(xv[4*g])   | ((unsigned)f2bf(xv[4*g+1]) << 16);
        w.w = (unsigned)f2bf(xv[4*g+2]) | ((unsigned)f2bf(xv[4*g+3]) << 16);
        *reinterpret_cast<uint4*>(p + g*8) = w;
    }
}
__device__ __forceinline__ void ld_nrec16(const unsigned short* p, float* pa, float* xv) {
    #pragma unroll
    for (int g = 0; g < 4; ++g) {
        uint4 w = *reinterpret_cast<const uint4*>(p + g*8);
        unpk4(make_uint2(w.x, w.y), pa + 4*g);
        unpk4(make_uint2(w.z, w.w), xv + 4*g);
    }
}
__device__ __forceinline__ void ld_X16(const unsigned short* p, float* xv) {
    #pragma unroll
    for (int g = 0; g < 4; ++g) {
        uint2 w = *reinterpret_cast<const uint2*>(p + g*8 + 4);
        unpk4(w, xv + 4*g);
    }
}

__global__ void kzero(float4* p, int n4) {
    int i = blockIdx.x * blockDim.x + threadIdx.x;
    if (i < n4) p[i] = make_float4(0.f, 0.f, 0.f, 0.f);
}

// ---------------- build: two-level counting sort (round-8 verbatim) ----------------

__global__ void khist1(const int* __restrict__ ei, int* __restrict__ hist) {
    __shared__ int h[NBKT];
    int blk = blockIdx.x, tid = threadIdx.x;
    for (int b = tid; b < NBKT; b += 256) h[b] = 0;
    __syncthreads();
    int e0 = blk * EPB1;
    for (int e = e0 + tid; e < e0 + EPB1; e += 256)
        atomicAdd(&h[ei[NE + e] >> BSHIFT], 1);     // LDS atomic
    __syncthreads();
    for (int b = tid; b < NBKT; b += 256) hist[b * NBLK1 + blk] = h[b];
}

__global__ void kscan_a(int* __restrict__ hist, int* __restrict__ binsum) {
    __shared__ int s[NBLK1];
    int b = blockIdx.x, t = threadIdx.x;
    int v = hist[b * NBLK1 + t];
    s[t] = v; __syncthreads();
    for (int off = 1; off < NBLK1; off <<= 1) {
        int u = (t >= off) ? s[t - off] : 0;
        __syncthreads();
        s[t] += u;
        __syncthreads();
    }
    hist[b * NBLK1 + t] = s[t] - v;
    if (t == NBLK1 - 1) binsum[b] = s[t];
}

__global__ void kscan_b(const int* __restrict__ binsum, int* __restrict__ binbase,
                        int* __restrict__ start) {
    __shared__ int s[1024];
    int t = threadIdx.x;
    int v = (t < NBKT) ? binsum[t] : 0;
    s[t] = v; __syncthreads();
    for (int off = 1; off < 1024; off <<= 1) {
        int u = (t >= off) ? s[t - off] : 0;
        __syncthreads();
        s[t] += u;
        __syncthreads();
    }
    if (t < NBKT) binbase[t] = s[t] - v;
    if (t == NBKT - 1) binbase[NBKT] = s[t];        // == NE
    if (t == 0) start[NN] = NE;
}

__global__ void kscatter1(const int* __restrict__ ei, const float* __restrict__ ea,
                          const int* __restrict__ hist, const int* __restrict__ binbase,
                          uint4* __restrict__ brec16) {
    __shared__ int cur[NBKT];
    int blk = blockIdx.x, tid = threadIdx.x;
    for (int b = tid; b < NBKT; b += 256)
        cur[b] = binbase[b] + hist[b * NBLK1 + blk];
    __syncthreads();
    int e0 = blk * EPB1;
    for (int e = e0 + tid; e < e0 + EPB1; e += 256) {
        int s = ei[e], d = ei[NE + e];
        float f0 = ea[(size_t)3*e], f1 = ea[(size_t)3*e+1], f2 = ea[(size_t)3*e+2];
        int pos = atomicAdd(&cur[d >> BSHIFT], 1);  // LDS atomic
        unsigned long long u = (unsigned long long)(unsigned int)s
                             | ((unsigned long long)(unsigned int)d << 17)
                             | ((unsigned long long)(unsigned int)e << 34);
        uint4 r;
        r.x = (unsigned int)u;
        r.y = (unsigned int)(u >> 32);
        r.z = (unsigned int)f2bf(f0) | ((unsigned int)f2bf(f1) << 16);
        r.w = (unsigned int)f2bf(f2);
        brec16[pos] = r;
    }
}

__global__ void kbucket(const uint4* __restrict__ brec16, const int* __restrict__ binbase,
                        unsigned long long* __restrict__ srec, unsigned int* __restrict__ ea_s,
                        int* __restrict__ start) {
    __shared__ int cnt[128];
    __shared__ int off[128];
    __shared__ int cur[128];
    int bkt = blockIdx.x, t = threadIdx.x;
    int base = binbase[bkt], end = binbase[bkt + 1];
    if (t < 128) cnt[t] = 0;
    __syncthreads();
    for (int j = base + t; j < end; j += 256) {
        uint4 r = brec16[j];
        int dl = (int)(((r.x >> 17) | (r.y << 15)) & 0x1FFFFu) & LMASK;
        atomicAdd(&cnt[dl], 1);
    }
    __syncthreads();
    if (t < 128) { off[t] = cnt[t]; }
    __syncthreads();
    for (int o = 1; o < 128; o <<= 1) {
        int u = (t < 128 && t >= o) ? off[t - o] : 0;
        __syncthreads();
        if (t < 128) off[t] += u;
        __syncthreads();
    }
    if (t < 128) {
        int excl = off[t] - cnt[t];
        int node = bkt * 128 + t;
        if (node < NN) start[node] = base + excl;
        cur[t] = base + excl;
    }
    __syncthreads();
    for (int j = base + t; j < end; j += 256) {
        uint4 r = brec16[j];
        int dl = (int)(((r.x >> 17) | (r.y << 15)) & 0x1FFFFu) & LMASK;
        int p = atomicAdd(&cur[dl], 1);
        srec[p] = (unsigned long long)r.x | ((unsigned long long)r.y << 32);
        *reinterpret_cast<uint2*>(&ea_s[(size_t)2*p]) = make_uint2(r.z, r.w);
    }
}

// ---------------- node-side kernels (round-10/11 verbatim, verified) ----------------

__global__ void prep1(const float* __restrict__ x, const float* __restrict__ ew1,
                      unsigned short* __restrict__ nrec, unsigned short* __restrict__ Pc) {
    int n = blockIdx.x * blockDim.x + threadIdx.x;
    if (n >= NN) return;
    float x0 = x[3*n], x1 = x[3*n+1], x2 = x[3*n+2];
    float pa[16], pc[16], xv[16];
    #pragma unroll
    for (int j = 0; j < 16; ++j) {
        pa[j] = x0*ew1[0*16+j] + x1*ew1[1*16+j] + x2*ew1[2*16+j];
        pc[j] = x0*ew1[6*16+j] + x1*ew1[7*16+j] + x2*ew1[8*16+j];
        xv[j] = 0.f;
    }
    xv[0] = x0; xv[1] = x1; xv[2] = x2;
    st_nrec16(nrec + (size_t)n*32, pa, xv);
    stbf16x16(Pc + (size_t)n*16, pc);
}

__global__ void conv1_node(const float* __restrict__ agg, const float* __restrict__ x,
                           const float* __restrict__ nw1, const float* __restrict__ nb1,
                           const float* __restrict__ nw2, const float* __restrict__ nb2,
                           const float* __restrict__ next_ew1,
                           unsigned short* __restrict__ nrec, unsigned short* __restrict__ Pc) {
    int n = blockIdx.x * blockDim.x + threadIdx.x;
    if (n >= NN) return;
    float o0 = agg[(size_t)n*16+0] + x[3*n];
    float o1 = agg[(size_t)n*16+1] + x[3*n+1];
    float o2 = agg[(size_t)n*16+2] + x[3*n+2];
    float h[16];
    #pragma unroll
    for (int j = 0; j < 16; ++j)
        h[j] = fmaxf(nb1[j] + o0*nw1[0*16+j] + o1*nw1[1*16+j] + o2*nw1[2*16+j], 0.f);
    float xn[16];
    #pragma unroll
    for (int j = 0; j < 16; ++j) {
        float a = nb2[j];
        #pragma unroll
        for (int i = 0; i < 16; ++i) a = fmaf(h[i], nw2[i*16+j], a);
        xn[j] = fmaxf(a, 0.f);
    }
    float pa[16], pc[16];
    #pragma unroll
    for (int j = 0; j < 16; ++j) {
        float sa = 0.f, sc = 0.f;
        #pragma unroll
        for (int i = 0; i < 16; ++i) {
            sa = fmaf(xn[i], next_ew1[i*16+j], sa);
            sc = fmaf(xn[i], next_ew1[(32+i)*16+j], sc);
        }
        pa[j] = sa; pc[j] = sc;
    }
    st_nrec16(nrec + (size_t)n*32, pa, xn);
    stbf16x16(Pc + (size_t)n*16, pc);
}

__global__ void node_mid(const float* __restrict__ agg,
                         const float* __restrict__ nw1, const float* __restrict__ nb1,
                         const float* __restrict__ nw2, const float* __restrict__ nb2,
                         const float* __restrict__ next_ew1,
                         unsigned short* nrec, unsigned short* __restrict__ Pc) {
    int n = blockIdx.x * blockDim.x + threadIdx.x;
    if (n >= NN) return;
    float o[16];
    ld_X16(nrec + (size_t)n*32, o);
    #pragma unroll
    for (int j = 0; j < 16; ++j) o[j] += agg[(size_t)n*16 + j];
    float h[16];
    #pragma unroll
    for (int j = 0; j < 16; ++j) {
        float a = nb1[j];
        #pragma unroll
        for (int i = 0; i < 16; ++i) a = fmaf(o[i], nw1[i*16+j], a);
        h[j] = fmaxf(a, 0.f);
    }
    float xn[16];
    #pragma unroll
    for (int j = 0; j < 16; ++j) {
        float a = nb2[j];
        #pragma unroll
        for (int i = 0; i < 16; ++i) a = fmaf(h[i], nw2[i*16+j], a);
        xn[j] = fmaxf(a, 0.f);
    }
    float pa[16], pc[16];
    #pragma unroll
    for (int j = 0; j < 16; ++j) {
        float sa = 0.f, sc = 0.f;
        #pragma unroll
        for (int i = 0; i < 16; ++i) {
            sa = fmaf(xn[i], next_ew1[i*16+j], sa);
            sc = fmaf(xn[i], next_ew1[(32+i)*16+j], sc);
        }
        pa[j] = sa; pc[j] = sc;
    }
    st_nrec16(nrec + (size_t)n*32, pa, xn);
    stbf16x16(Pc + (size_t)n*16, pc);
}

__global__ void node_last(const float* __restrict__ agg, const unsigned short* __restrict__ nrec,
                          const float* __restrict__ nw1, const float* __restrict__ nb1,
                          const float* __restrict__ nw2, const float* __restrict__ nb2,
                          const float* __restrict__ hw1, const float* __restrict__ hb1,
                          const float* __restrict__ hw2, const float* __restrict__ hb2,
                          float* __restrict__ out_n) {
    int n = blockIdx.x * blockDim.x + threadIdx.x;
    if (n >= NN) return;
    float o[16];
    ld_X16(nrec + (size_t)n*32, o);
    #pragma unroll
    for (int j = 0; j < 16; ++j) o[j] += agg[(size_t)n*16 + j];
    float h[16];
    #pragma unroll
    for (int j = 0; j < 16; ++j) {
        float a = nb1[j];
        #pragma unroll
        for (int i = 0; i < 16; ++i) a = fmaf(o[i], nw1[i*16+j], a);
        h[j] = fmaxf(a, 0.f);
    }
    float xn[16];
    #pragma unroll
    for (int j = 0; j < 16; ++j) {
        float a = nb2[j];
        #pragma unroll
        for (int i = 0; i < 16; ++i) a = fmaf(h[i], nw2[i*16+j], a);
        xn[j] = fmaxf(a, 0.f);
    }
    float g[16];
    #pragma unroll
    for (int j = 0; j < 16; ++j) {
        float a = hb1[j];
        #pragma unroll
        for (int i = 0; i < 16; ++i) a = fmaf(xn[i], hw1[i*16+j], a);
        g[j] = fmaxf(a, 0.f);
    }
    #pragma unroll
    for (int k = 0; k < 3; ++k) {
        float a = hb2[k];
        #pragma unroll
        for (int i = 0; i < 16; ++i) a = fmaf(g[i], hw2[i*3+k], a);
        out_n[(size_t)n*3 + k] = a;
    }
}

// ---- fused convs: slot-parallel MLP + block-level SEGMENTED reduction ----

// conv1: MLP from ea; msg3. NE = 12500*256 exactly -> every block full.
__global__ void conv1E(const unsigned long long* __restrict__ srec,
                       const unsigned int* __restrict__ ea_s,
                       const unsigned short* __restrict__ nrec, const unsigned short* __restrict__ Pcb,
                       const float* __restrict__ ew1, const float* __restrict__ eb1,
                       const float* __restrict__ ew2, const float* __restrict__ eb2,
                       unsigned short* __restrict__ ebuf, float* agg) {
    __shared__ float smsg[256 * 5];
    __shared__ int st_[256];
    __shared__ int scn[256];
    __shared__ int segofs[257];
    __shared__ int nsegS;
    int tid = threadIdx.x;
    int j = blockIdx.x * 256 + tid;
    unsigned long long sr = srec[j];
    int s = (int)(sr & 0x1FFFFu);
    int t = (int)((sr >> 17) & 0x1FFFFu);
    float pa[16], xv[16], pc[16];
    ld_nrec16(nrec + (size_t)s*32, pa, xv);
    ldbf16x16(Pcb + (size_t)t*16, pc);
    uint2 eaw = *reinterpret_cast<const uint2*>(&ea_s[(size_t)2*j]);
    float e0 = bf2f(eaw.x & 0xffffu), e1 = bf2f(eaw.x >> 16), e2 = bf2f(eaw.y & 0xffffu);
    float h[16];
    #pragma unroll
    for (int jj = 0; jj < 16; ++jj) {
        float a = pa[jj] + pc[jj] + eb1[jj]
                + e0*ew1[3*16+jj] + e1*ew1[4*16+jj] + e2*ew1[5*16+jj];
        h[jj] = fmaxf(a, 0.f);
    }
    float h2[16];
    #pragma unroll
    for (int jj = 0; jj < 16; ++jj) {
        float a = eb2[jj];
        #pragma unroll
        for (int i = 0; i < 16; ++i) a = fmaf(h[i], ew2[i*16+jj], a);
        h2[jj] = fmaxf(a, 0.f);
    }
    stbf16x16(ebuf + (size_t)j*16, h2);
    st_[tid] = t;
    smsg[tid*5 + 0] = fmaxf(xv[0] + e0, 0.f);
    smsg[tid*5 + 1] = fmaxf(xv[1] + e1, 0.f);
    smsg[tid*5 + 2] = fmaxf(xv[2] + e2, 0.f);
    __syncthreads();
    int flag = (tid == 0 || st_[tid-1] != t) ? 1 : 0;
    scn[tid] = flag; __syncthreads();
    for (int off = 1; off < 256; off <<= 1) {
        int u = (tid >= off) ? scn[tid - off] : 0;
        __syncthreads();
        scn[tid] += u;
        __syncthreads();
    }
    if (flag) segofs[scn[tid] - 1] = tid;
    if (tid == 255) { nsegS = scn[255]; segofs[scn[255]] = 256; }
    __syncthreads();
    int nseg = nsegS;
    for (int p = tid; p < nseg * 4; p += 256) {
        int seg = p >> 2, d = p & 3;
        if (d == 3) continue;
        int k0 = segofs[seg], k1 = segofs[seg + 1];
        float a = 0.f;
        for (int k = k0; k < k1; ++k) a += smsg[k*5 + d];
        int node = st_[k0];
        if (seg == 0 || seg == nseg - 1)
            atomicAdd(&agg[(size_t)node*16 + d], a);
        else
            agg[(size_t)node*16 + d] = a;
    }
}

// conv2/3: MLP from ebuf (in place); msg16.
__global__ void convE(const unsigned long long* __restrict__ srec,
                      unsigned short* ebuf,
                      const unsigned short* __restrict__ nrec, const unsigned short* __restrict__ Pcb,
                      const float* __restrict__ ew1, const float* __restrict__ eb1,
                      const float* __restrict__ ew2, const float* __restrict__ eb2,
                      float* agg) {
    __shared__ float smsg[256 * 17];
    __shared__ int st_[256];
    __shared__ int scn[256];
    __shared__ int segofs[257];
    __shared__ int nsegS;
    int tid = threadIdx.x;
    int j = blockIdx.x * 256 + tid;
    unsigned long long sr = srec[j];
    int s = (int)(sr & 0x1FFFFu);
    int t = (int)((sr >> 17) & 0x1FFFFu);
    float pa[16], xv[16], pc[16], ein[16];
    ld_nrec16(nrec + (size_t)s*32, pa, xv);      // one 64B line: Pa + X
    ldbf16x16(Pcb + (size_t)t*16, pc);           // dst-grouped, cached
    ldbf16x16(ebuf + (size_t)j*16, ein);         // old edge feats (stream)
    float h[16];
    #pragma unroll
    for (int jj = 0; jj < 16; ++jj) h[jj] = pa[jj] + pc[jj] + eb1[jj];
    #pragma unroll
    for (int i = 0; i < 16; ++i) {
        #pragma unroll
        for (int jj = 0; jj < 16; ++jj) h[jj] = fmaf(ein[i], ew1[(16+i)*16+jj], h[jj]);
    }
    #pragma unroll
    for (int jj = 0; jj < 16; ++jj) h[jj] = fmaxf(h[jj], 0.f);
    float h2[16];
    #pragma unroll
    for (int jj = 0; jj < 16; ++jj) {
        float a = eb2[jj];
        #pragma unroll
        for (int i = 0; i < 16; ++i) a = fmaf(h[i], ew2[i*16+jj], a);
        h2[jj] = fmaxf(a, 0.f);
    }
    stbf16x16(ebuf + (size_t)j*16, h2);          // full 32B row, in place
    st_[tid] = t;
    #pragma unroll
    for (int d = 0; d < 16; ++d) smsg[tid*17 + d] = fmaxf(xv[d] + ein[d], 0.f);
    __syncthreads();
    int flag = (tid == 0 || st_[tid-1] != t) ? 1 : 0;
    scn[tid] = flag; __syncthreads();
    for (int off = 1; off < 256; off <<= 1) {
        int u = (tid >= off) ? scn[tid - off] : 0;
        __syncthreads();
        scn[tid] += u;
        __syncthreads();
    }
    if (flag) segofs[scn[tid] - 1] = tid;
    if (tid == 255) { nsegS = scn[255]; segofs[scn[255]] = 256; }
    __syncthreads();
    int nseg = nsegS;
    for (int p = tid; p < nseg * 16; p += 256) {
        int seg = p >> 4, d = p & 15;
        int k0 = segofs[seg], k1 = segofs[seg + 1];
        float a = 0.f;
        for (int k = k0; k < k1; ++k) a += smsg[k*17 + d];
        int node = st_[k0];
        if (seg == 0 || seg == nseg - 1)
            atomicAdd(&agg[(size_t)node*16 + d], a);   // boundary: <=2 segs/block
        else
            agg[(size_t)node*16 + d] = a;              // interior: plain store
    }
}

// conv3 edge head: stream ebuf3 + srec -> out_e scatter (after node_last).
__global__ void khead(const unsigned long long* __restrict__ srec,
                      const unsigned short* __restrict__ ebuf,
                      const float* __restrict__ hw1, const float* __restrict__ hb1,
                      const float* __restrict__ hw2, const float* __restrict__ hb2,
                      float* __restrict__ out_e) {
    int j = blockIdx.x * blockDim.x + threadIdx.x;
    if (j >= NE) return;
    unsigned long long sr = srec[j];
    int e = (int)(sr >> 34);
    float h2[16];
    ldbf16x16(ebuf + (size_t)j*16, h2);
    float g[16];
    #pragma unroll
    for (int jj = 0; jj < 16; ++jj) {
        float a = hb1[jj];
        #pragma unroll
        for (int i = 0; i < 16; ++i) a = fmaf(h2[i], hw1[i*16+jj], a);
        g[jj] = fmaxf(a, 0.f);
    }
    #pragma unroll
    for (int k = 0; k < 3; ++k) {
        float a = hb2[k];
        #pragma unroll
        for (int i = 0; i < 16; ++i) a = fmaf(g[i], hw2[i*3+k], a);
        out_e[(size_t)e*3 + k] = a;
    }
}

extern "C" void kernel_launch(void* const* d_in, const int* in_sizes, int n_in,
                              void* d_out, int out_size, void* d_ws, size_t ws_size,
                              hipStream_t stream) {
    const float* x  = (const float*)d_in[0];
    const float* ea = (const float*)d_in[1];
    const int*   ei = (const int*)d_in[2];
    const float *c1_ew1 = (const float*)d_in[3],  *c1_eb1 = (const float*)d_in[4];
    const float *c1_ew2 = (const float*)d_in[5],  *c1_eb2 = (const float*)d_in[6];
    const float *c1_nw1 = (const float*)d_in[7],  *c1_nb1 = (const float*)d_in[8];
    const float *c1_nw2 = (const float*)d_in[9],  *c1_nb2 = (const float*)d_in[10];
    const float *c2_ew1 = (const float*)d_in[11], *c2_eb1 = (const float*)d_in[12];
    const float *c2_ew2 = (const float*)d_in[13], *c2_eb2 = (const float*)d_in[14];
    const float *c2_nw1 = (const float*)d_in[15], *c2_nb1 = (const float*)d_in[16];
    const float *c2_nw2 = (const float*)d_in[17], *c2_nb2 = (const float*)d_in[18];
    const float *c3_ew1 = (const float*)d_in[19], *c3_eb1 = (const float*)d_in[20];
    const float *c3_ew2 = (const float*)d_in[21], *c3_eb2 = (const float*)d_in[22];
    const float *c3_nw1 = (const float*)d_in[23], *c3_nb1 = (const float*)d_in[24];
    const float *c3_nw2 = (const float*)d_in[25], *c3_nb2 = (const float*)d_in[26];
    const float *node_w1 = (const float*)d_in[27], *node_b1 = (const float*)d_in[28];
    const float *node_w2 = (const float*)d_in[29], *node_b2 = (const float*)d_in[30];
    const float *edge_w1 = (const float*)d_in[31], *edge_b1 = (const float*)d_in[32];
    const float *edge_w2 = (const float*)d_in[33], *edge_b2 = (const float*)d_in[34];

    // ---- ws carve-up (137.6 MB) ----
    char* w = (char*)d_ws;
    unsigned short* ebuf = (unsigned short*)w;               // NE*32; build scratch aliases inside:
    uint4* brec16 = (uint4*)w;                               //   NE*16 = 51.2 MB
    int* hist   = (int*)(w + (size_t)NE*16);                 //   NBKT*NBLK1*4 = 3.2 MB
    int* binsum = hist + NBKT * NBLK1;
    int* binbase = binsum + NBKT;
    w += (size_t)NE * 32;
    unsigned long long* srec = (unsigned long long*)w;  w += (size_t)NE * 8;   // 25.6 MB
    unsigned short* nrec = (unsigned short*)w;          w += (size_t)NN * 64;  // 6.4 MB
    unsigned short* Pc   = (unsigned short*)w;          w += (size_t)NN * 32;  // 3.2 MB

    // ---- d_out overlays ----
    float* out_n = (float*)d_out;                      // N*3 floats
    float* out_e = out_n + (size_t)NN * 3;             // E*3 floats
    int* start = (int*)out_n;                          // build scratch, dead before node_last
    unsigned int* ea_s = (unsigned int*)out_e;                 // NE*8 = 25.6 MB
    float* agg = (float*)((char*)out_e + (size_t)NE * 8);      // N*16 f32 = 6.4 MB

    const int B = 256;
    const int gn = (NN + B - 1) / B;                 // 391
    const int ge = NE / B;                           // 12500 exact
    const int gz = (NN * 16 / 4 + B - 1) / B;        // 1563

    // ---- build (no global atomics; round-8 verbatim) ----
    khist1<<<NBLK1, B, 0, stream>>>(ei, hist);
    kscan_a<<<NBKT, NBLK1, 0, stream>>>(hist, binsum);
    kscan_b<<<1, 1024, 0, stream>>>(binsum, binbase, start);
    kscatter1<<<NBLK1, B, 0, stream>>>(ei, ea, hist, binbase, brec16);
    kbucket<<<NBKT, B, 0, stream>>>(brec16, binbase, srec, ea_s, start);

    // ---- conv1 (conv1E clobbers brec16/hist/binbase region via ebuf — all dead) ----
    prep1<<<gn, B, 0, stream>>>(x, c1_ew1, nrec, Pc);
    kzero<<<gz, B, 0, stream>>>((float4*)agg, NN * 16 / 4);
    conv1E<<<ge, B, 0, stream>>>(srec, ea_s, nrec, Pc,
                                 c1_ew1, c1_eb1, c1_ew2, c1_eb2, ebuf, agg);
    conv1_node<<<gn, B, 0, stream>>>(agg, x, c1_nw1, c1_nb1, c1_nw2, c1_nb2,
                                     c2_ew1, nrec, Pc);
    // ---- conv2 ----
    kzero<<<gz, B, 0, stream>>>((float4*)agg, NN * 16 / 4);
    convE<<<ge, B, 0, stream>>>(srec, ebuf, nrec, Pc,
                                c2_ew1, c2_eb1, c2_ew2, c2_eb2, agg);
    node_mid<<<gn, B, 0, stream>>>(agg, c2_nw1, c2_nb1, c2_nw2, c2_nb2,
                                   c3_ew1, nrec, Pc);
    // ---- conv3 (convE writes agg; node_last consumes agg + writes out_n;
    //      khead finally overwrites ea_s/agg region with real out_e) ----
    kzero<<<gz, B, 0, stream>>>((float4*)agg, NN * 16 / 4);
    convE<<<ge, B, 0, stream>>>(srec, ebuf, nrec, Pc,
                                c3_ew1, c3_eb1, c3_ew2, c3_eb2, agg);
    node_last<<<gn, B, 0, stream>>>(agg, nrec, c3_nw1, c3_nb1, c3_nw2, c3_nb2,
                                    node_w1, node_b1, node_w2, node_b2, out_n);
    khead<<<ge, B, 0, stream>>>(srec, ebuf, edge_w1, edge_b1, edge_w2, edge_b2, out_e);
}